// Round 6
// baseline (445.304 us; speedup 1.0000x reference)
//
#include <hip/hip_runtime.h>

// KPConv simple block: grid ball query + KPConv(MFMA) + BN + LeakyReLU
// B=8, N=4096 -> M=32768; C_IN=64, C_OUT=128, K=15 kernel pts, nn<=34.
//
// Exact simplification: influence w = max(1 - d/0.04, 0) with ||kp||<=0.042
// => neighbors with ||rel|| >= 0.082 contribute 0; unordered within-0.082
// set (cap 34) == reference top-k result.
//
// R6 = R5 (chunked candidate pipeline) + 2 fixes:
//  (a) feature staging loaded only 32B of each 64B half-row -> stale LDS
//      read as bf16 (NaN source).  Now 4x uint4 per staging thread.
//  (b) rowrs/rowlen/pfx sized 144/145 (16 sorted queries crossing a z-layer
//      can span up to 144 candidate x-rows; 48 could overflow).

#define NB     8
#define NPTS   4096
#define M_TOT  32768
#define CIN    64
#define COUT   128
#define NKP    15
#define MAXNN  34
#define NCELL  1728            // 12^3
#define MAXROWS 144
#define R2EFF  (0.082f * 0.082f)
#define KP_INV 25.0f           // 1 / KP_EXTENT(0.04)
#define NEG_SLOPE 0.2f
#define KTOT   960             // NKP * CIN
#define WFPAD  968             // LDS wf row stride (bf16), 16B-aligned

typedef float f32x4_t __attribute__((ext_vector_type(4)));
typedef short bf16x8_t __attribute__((ext_vector_type(8)));

__device__ __forceinline__ unsigned short f2bf(float f) {
  union { float f; unsigned u; } v; v.f = f;
  unsigned r = v.u + 0x7FFF + ((v.u >> 16) & 1);   // RNE
  return (unsigned short)(r >> 16);
}
__device__ __forceinline__ float bf2f(unsigned short s) {
  union { unsigned u; float f; } v; v.u = ((unsigned)s) << 16; return v.f;
}
__device__ __forceinline__ int cell_of(float x, float y, float z) {
  int cx = (int)(x * 12.f); cx = cx > 11 ? 11 : cx;
  int cy = (int)(y * 12.f); cy = cy > 11 ? 11 : cy;
  int cz = (int)(z * 12.f); cz = cz > 11 ? 11 : cz;
  return (cz * 12 + cy) * 12 + cx;
}

// ---------------------------------------------------------------------------
// K0a: per-cell histogram
// ---------------------------------------------------------------------------
__global__ __launch_bounds__(256) void k0a_hist(
    const float* __restrict__ xyz, int* __restrict__ cellcnt)
{
  const int pt = blockIdx.x * 256 + threadIdx.x;
  const float x = xyz[pt * 3], y = xyz[pt * 3 + 1], z = xyz[pt * 3 + 2];
  const int b = pt >> 12;
  atomicAdd(&cellcnt[b * NCELL + cell_of(x, y, z)], 1);
}

// ---------------------------------------------------------------------------
// K0b: blocks 0..7 = per-batch exclusive scan; blocks 8..67 = W transpose
// ---------------------------------------------------------------------------
__global__ __launch_bounds__(256) void k0b_scan_kW(
    const int* __restrict__ cellcnt, int* __restrict__ cellstart,
    const float* __restrict__ W, unsigned short* __restrict__ Wt)
{
  if (blockIdx.x >= 8) {
    const int idx = (blockIdx.x - 8) * 256 + threadIdx.x;  // 15360
    const int n = idx & 127, kg = idx >> 7;
    union { unsigned short s[8]; uint4 v; } u;
    #pragma unroll
    for (int j = 0; j < 8; j++)
      u.s[j] = f2bf(W[(size_t)(kg * 8 + j) * COUT + n]);
    *(uint4*)&Wt[(size_t)n * KTOT + kg * 8] = u.v;
    return;
  }
  __shared__ int ps[256];
  const int b = blockIdx.x, t = threadIdx.x;
  int local[7], s = 0;
  #pragma unroll
  for (int i = 0; i < 7; i++) {
    const int cid = t * 7 + i;
    const int c = (cid < NCELL) ? cellcnt[b * NCELL + cid] : 0;
    local[i] = c; s += c;
  }
  ps[t] = s; __syncthreads();
  for (int off = 1; off < 256; off <<= 1) {
    int v = (t >= off) ? ps[t - off] : 0;
    __syncthreads();
    ps[t] += v;
    __syncthreads();
  }
  int run = ps[t] - s;
  #pragma unroll
  for (int i = 0; i < 7; i++) {
    const int cid = t * 7 + i;
    if (cid < NCELL) { cellstart[b * 1729 + cid] = run; run += local[i]; }
  }
  if (t == 255) cellstart[b * 1729 + NCELL] = ps[255];
}

// ---------------------------------------------------------------------------
// K0c: counting-sort scatter -> qorder + sorted xyz float4
// ---------------------------------------------------------------------------
__global__ __launch_bounds__(256) void k0c_scatter(
    const float* __restrict__ xyz, const int* __restrict__ cellstart,
    int* __restrict__ cellfill, int* __restrict__ qorder,
    float4* __restrict__ xyzs)
{
  const int pt = blockIdx.x * 256 + threadIdx.x;
  const float x = xyz[pt * 3], y = xyz[pt * 3 + 1], z = xyz[pt * 3 + 2];
  const int b = pt >> 12;
  const int cid = cell_of(x, y, z);
  const int slot = atomicAdd(&cellfill[b * NCELL + cid], 1);
  const int pos = b * NPTS + cellstart[b * 1729 + cid] + slot;
  qorder[pos] = pt;
  xyzs[pos] = make_float4(x, y, z, 0.f);
}

// ---------------------------------------------------------------------------
// Kf: feats -> sorted bf16 (gathered 32B reads, coalesced 16B writes)
// ---------------------------------------------------------------------------
__global__ __launch_bounds__(256) void kf_sortfeats(
    const float* __restrict__ feats, const int* __restrict__ qorder,
    unsigned short* __restrict__ fsorted)
{
  const int idx = blockIdx.x * 256 + threadIdx.x;  // 262144
  const int pos = idx >> 3, cg = idx & 7;
  const int q = qorder[pos];
  const float* src = &feats[(size_t)q * CIN + cg * 8];
  float4 a = *(const float4*)src, c = *(const float4*)(src + 4);
  union { unsigned short s[8]; uint4 v; } u;
  u.s[0] = f2bf(a.x); u.s[1] = f2bf(a.y); u.s[2] = f2bf(a.z); u.s[3] = f2bf(a.w);
  u.s[4] = f2bf(c.x); u.s[5] = f2bf(c.y); u.s[6] = f2bf(c.z); u.s[7] = f2bf(c.w);
  *(uint4*)&fsorted[(size_t)pos * CIN + cg * 8] = u.v;
}

// ---------------------------------------------------------------------------
// K2: fused ball-query + KPConv, chunked candidate pipeline.
// 2048 blocks x 256 thr; block = 16 consecutive sorted queries.
//  X: t0-63 test one candidate each vs 16 queries (hits -> weight rows in
//     LDS); t64-191 stage the chunk's 64 bf16 feature rows (2 thr x 64B).
//  Y: all 4 waves accumulate wf from LDS only.
//  Epilogue: MFMA GEMM vs global Wt + BN partial atomics + scatter store.
// ---------------------------------------------------------------------------
__global__ __launch_bounds__(256, 2) void k2_conv(
    const float4* __restrict__ xyzs, const unsigned short* __restrict__ fsorted,
    const float* __restrict__ kpts, const int* __restrict__ cellstart,
    const int* __restrict__ qorder, const unsigned short* __restrict__ Wt,
    float* __restrict__ out, float* __restrict__ psum,
    float* __restrict__ psumsq)
{
  __shared__ short  wf[16][WFPAD];       // 30976 B
  __shared__ float  w2[16][MAXNN][16];   // 34816 B  weight rows (f32)
  __shared__ short  fcache[64][72];      //  9216 B  chunk bf16 features
  __shared__ short  lid[16][MAXNN];      //  1088 B  local candidate idx
  __shared__ float4 qd[16];              //   256 B
  __shared__ int    qm[16];
  __shared__ int    cnts[16], prev[16];
  __shared__ float  kp[NKP][4];          //   240 B
  __shared__ int    rowrs[MAXROWS], rowlen[MAXROWS], pfx[MAXROWS + 1];
  __shared__ int    meta[6];             // ylo yspan zlo xlo xhi nrows
  __shared__ int    qcell[16][3];

  const int tid = threadIdx.x;
  const int w   = tid >> 6;
  const int L   = tid & 63;
  const int m0  = blockIdx.x * 16;
  const int b   = m0 >> 12;

  if (tid < NKP * 3) {
    int k = tid / 3, c = tid - k * 3;
    kp[k][c] = kpts[tid];
  }
  if (tid < 16) {
    float4 Q = xyzs[m0 + tid];
    qd[tid] = Q; qm[tid] = qorder[m0 + tid]; cnts[tid] = 0;
    int cx = (int)(Q.x * 12.f); cx = cx > 11 ? 11 : cx;
    int cy = (int)(Q.y * 12.f); cy = cy > 11 ? 11 : cy;
    int cz = (int)(Q.z * 12.f); cz = cz > 11 ? 11 : cz;
    qcell[tid][0] = cx; qcell[tid][1] = cy; qcell[tid][2] = cz;
  }
  __syncthreads();

  if (tid == 0) {
    int x0 = 12, x1 = -1, y0 = 12, y1 = -1, z0 = 12, z1 = -1;
    for (int i = 0; i < 16; i++) {
      int cx = qcell[i][0], cy = qcell[i][1], cz = qcell[i][2];
      x0 = cx < x0 ? cx : x0; x1 = cx > x1 ? cx : x1;
      y0 = cy < y0 ? cy : y0; y1 = cy > y1 ? cy : y1;
      z0 = cz < z0 ? cz : z0; z1 = cz > z1 ? cz : z1;
    }
    x0 = x0 > 0 ? x0 - 1 : 0;  x1 = x1 < 11 ? x1 + 1 : 11;
    y0 = y0 > 0 ? y0 - 1 : 0;  y1 = y1 < 11 ? y1 + 1 : 11;
    z0 = z0 > 0 ? z0 - 1 : 0;  z1 = z1 < 11 ? z1 + 1 : 11;
    int nr = (y1 - y0 + 1) * (z1 - z0 + 1);
    meta[0] = y0; meta[1] = y1 - y0 + 1; meta[2] = z0;
    meta[3] = x0; meta[4] = x1;
    meta[5] = nr > MAXROWS ? MAXROWS : nr;
  }
  __syncthreads();

  const int nrows = meta[5], yspan = meta[1];
  if (tid < nrows) {
    const int z = meta[2] + tid / yspan, y = meta[0] + tid % yspan;
    const int base = b * 1729 + (z * 12 + y) * 12;
    const int rs = cellstart[base + meta[3]];
    rowrs[tid]  = rs;
    rowlen[tid] = cellstart[base + meta[4] + 1] - rs;
  }
  __syncthreads();
  if (tid == 0) {
    int run = 0;
    for (int r = 0; r < nrows; r++) { pfx[r] = run; run += rowlen[r]; }
    pfx[nrows] = run;
  }
  __syncthreads();
  const int T = pfx[nrows];

  float acc4[4][NKP];
  #pragma unroll
  for (int qi = 0; qi < 4; qi++)
    #pragma unroll
    for (int k = 0; k < NKP; k++) acc4[qi][k] = 0.f;

  int rloc = 0;   // monotone row cursor (per-thread; t advances by 64/chunk)

  for (int tb = 0; tb < T; tb += 64) {
    // ---- X: search (t0-63) + feature staging (t64-191) ----
    if (tid < 16) prev[tid] = cnts[tid];
    if (tid < 64) {
      const int t = tb + tid;
      if (t < T) {
        while (t >= pfx[rloc + 1]) rloc++;
        const int pos = rowrs[rloc] + (t - pfx[rloc]);
        const float4 P = xyzs[b * NPTS + pos];
        #pragma unroll
        for (int q = 0; q < 16; q++) {
          const float4 Q = qd[q];
          const float dx = P.x - Q.x, dy = P.y - Q.y, dz = P.z - Q.z;
          const float d2 = dx * dx + dy * dy + dz * dz;
          if (d2 <= R2EFF) {
            const int slot = atomicAdd(&cnts[q], 1);
            if (slot < MAXNN) {
              lid[q][slot] = (short)tid;
              float* wr = w2[q][slot];
              #pragma unroll
              for (int k = 0; k < NKP; k++) {
                const float ex = dx - kp[k][0];
                const float ey = dy - kp[k][1];
                const float ez = dz - kp[k][2];
                wr[k] = fmaxf(1.f - sqrtf(ex*ex + ey*ey + ez*ez) * KP_INV, 0.f);
              }
              wr[15] = 0.f;
            }
          }
        }
      }
    } else if (tid < 192) {
      const int i = (tid - 64) >> 1, h = (tid - 64) & 1;   // 2 thr/row
      const int t = tb + i;
      if (t < T) {
        while (t >= pfx[rloc + 1]) rloc++;
        const int pos = rowrs[rloc] + (t - pfx[rloc]);
        // full 64B half-row: 4 x uint4 (R5 bug: only 2 were loaded)
        const uint4* src =
            (const uint4*)&fsorted[(size_t)(b * NPTS + pos) * CIN + h * 32];
        uint4 v0 = src[0], v1 = src[1], v2 = src[2], v3 = src[3];
        uint4* dst = (uint4*)&fcache[i][h * 32];
        dst[0] = v0; dst[1] = v1; dst[2] = v2; dst[3] = v3;
      }
    }
    __syncthreads();

    // ---- Y: accumulate this chunk's neighbors from LDS ----
    #pragma unroll
    for (int qi = 0; qi < 4; qi++) {
      const int q = w * 4 + qi;
      const int s0 = prev[q];
      int s1 = cnts[q]; s1 = s1 > MAXNN ? MAXNN : s1;
      for (int s = s0; s < s1; s++) {
        const int li = lid[q][s];
        const float f = bf2f((unsigned short)fcache[li][L]);
        const float* wr = w2[q][s];
        float4 w0 = *(const float4*)(wr + 0);
        float4 w1 = *(const float4*)(wr + 4);
        float4 wv2 = *(const float4*)(wr + 8);
        float4 w3 = *(const float4*)(wr + 12);
        acc4[qi][0]  += w0.x * f;  acc4[qi][1]  += w0.y * f;
        acc4[qi][2]  += w0.z * f;  acc4[qi][3]  += w0.w * f;
        acc4[qi][4]  += w1.x * f;  acc4[qi][5]  += w1.y * f;
        acc4[qi][6]  += w1.z * f;  acc4[qi][7]  += w1.w * f;
        acc4[qi][8]  += wv2.x * f; acc4[qi][9]  += wv2.y * f;
        acc4[qi][10] += wv2.z * f; acc4[qi][11] += wv2.w * f;
        acc4[qi][12] += w3.x * f;  acc4[qi][13] += w3.y * f;
        acc4[qi][14] += w3.z * f;
      }
    }
    __syncthreads();   // protect fcache/w2/lid/prev for next chunk
  }

  // ---- wf rows (bf16, MFMA A layout) ----
  #pragma unroll
  for (int qi = 0; qi < 4; qi++) {
    #pragma unroll
    for (int k = 0; k < NKP; k++)
      wf[w * 4 + qi][k * 64 + L] = (short)f2bf(acc4[qi][k]);
  }
  __syncthreads();

  // ---- MFMA GEMM: out[16][128] = wf[16][960] @ W[960][128] ----
  const int ln = L & 15;
  const int kh = L >> 4;
  const int colbase = w * 32;

  f32x4_t acc2[2];
  acc2[0] = (f32x4_t){0.f, 0.f, 0.f, 0.f};
  acc2[1] = (f32x4_t){0.f, 0.f, 0.f, 0.f};

  const unsigned short* Bp0 = &Wt[(size_t)(colbase + ln) * KTOT + kh * 8];
  const unsigned short* Bp1 = Bp0 + 16 * KTOT;
  const short* Ap = &wf[ln][kh * 8];

  #pragma unroll 3
  for (int kk = 0; kk < 30; kk++) {
    const int ko = kk * 32;
    bf16x8_t b0 = *(const bf16x8_t*)(Bp0 + ko);
    bf16x8_t b1 = *(const bf16x8_t*)(Bp1 + ko);
    bf16x8_t a0 = *(const bf16x8_t*)(Ap + ko);
    acc2[0] = __builtin_amdgcn_mfma_f32_16x16x32_bf16(a0, b0, acc2[0], 0, 0, 0);
    acc2[1] = __builtin_amdgcn_mfma_f32_16x16x32_bf16(a0, b1, acc2[1], 0, 0, 0);
  }

  // BN partials: reduce 16 rows across kh via shfl, atomic into psum[128]
  float s0 = 0.f, q0 = 0.f, s1 = 0.f, q1 = 0.f;
  #pragma unroll
  for (int j = 0; j < 4; j++) {
    s0 += acc2[0][j]; q0 += acc2[0][j] * acc2[0][j];
    s1 += acc2[1][j]; q1 += acc2[1][j] * acc2[1][j];
  }
  s0 += __shfl_xor(s0, 16); s0 += __shfl_xor(s0, 32);
  q0 += __shfl_xor(q0, 16); q0 += __shfl_xor(q0, 32);
  s1 += __shfl_xor(s1, 16); s1 += __shfl_xor(s1, 32);
  q1 += __shfl_xor(q1, 16); q1 += __shfl_xor(q1, 32);
  if (kh == 0) {
    atomicAdd(&psum[colbase + ln], s0);
    atomicAdd(&psumsq[colbase + ln], q0);
    atomicAdd(&psum[colbase + 16 + ln], s1);
    atomicAdd(&psumsq[colbase + 16 + ln], q1);
  }

  // C/D layout: col = lane&15, row = (lane>>4)*4 + reg; scatter via qm[]
  #pragma unroll
  for (int c = 0; c < 2; c++) {
    #pragma unroll
    for (int j = 0; j < 4; j++) {
      const int row = kh * 4 + j;
      out[(size_t)qm[row] * COUT + colbase + c * 16 + ln] = acc2[c][j];
    }
  }
}

// ---------------------------------------------------------------------------
// K4: BN finalize (per-block, from psum) + normalize + LeakyReLU
// ---------------------------------------------------------------------------
__global__ __launch_bounds__(256) void k4_norm(
    float* __restrict__ out, const float* __restrict__ psum,
    const float* __restrict__ psumsq, const float* __restrict__ gamma,
    const float* __restrict__ beta)
{
  __shared__ float a_s[128], b_s[128];
  if (threadIdx.x < 128) {
    const int d = threadIdx.x;
    double mu  = (double)psum[d] / (double)M_TOT;
    double var = (double)psumsq[d] / (double)M_TOT - mu * mu;  // biased
    float rstd = (float)(1.0 / sqrt(var + 1e-5));
    float a = rstd * gamma[d];
    a_s[d] = a;
    b_s[d] = beta[d] - (float)mu * a;
  }
  __syncthreads();
  const int idx = blockIdx.x * 256 + threadIdx.x;   // float4 index
  float4 v = ((const float4*)out)[idx];
  const int d0 = (idx * 4) & 127;
  float y0 = v.x * a_s[d0 + 0] + b_s[d0 + 0];
  float y1 = v.y * a_s[d0 + 1] + b_s[d0 + 1];
  float y2 = v.z * a_s[d0 + 2] + b_s[d0 + 2];
  float y3 = v.w * a_s[d0 + 3] + b_s[d0 + 3];
  v.x = y0 >= 0.f ? y0 : NEG_SLOPE * y0;
  v.y = y1 >= 0.f ? y1 : NEG_SLOPE * y1;
  v.z = y2 >= 0.f ? y2 : NEG_SLOPE * y2;
  v.w = y3 >= 0.f ? y3 : NEG_SLOPE * y3;
  ((float4*)out)[idx] = v;
}

// ---------------------------------------------------------------------------
extern "C" void kernel_launch(void* const* d_in, const int* in_sizes, int n_in,
                              void* d_out, int out_size, void* d_ws,
                              size_t ws_size, hipStream_t stream)
{
  const float* xyz   = (const float*)d_in[0];
  const float* feats = (const float*)d_in[1];
  const float* kpts  = (const float*)d_in[2];
  const float* W     = (const float*)d_in[3];
  const float* gamma = (const float*)d_in[4];
  const float* beta  = (const float*)d_in[5];
  float* out = (float*)d_out;

  char* ws = (char*)d_ws;
  int*            cellcnt   = (int*)(ws + 0);           //  55296 B ─┐
  int*            cellfill  = (int*)(ws + 55296);       //  55296 B  │ zeroed
  float*          psum      = (float*)(ws + 110592);    //    512 B  │
  float*          psumsq    = (float*)(ws + 111104);    //    512 B ─┘
  int*            cellstart = (int*)(ws + 111616);      //  55424 B
  int*            qorder    = (int*)(ws + 167040);      // 131072 B
  float4*         xyzs      = (float4*)(ws + 298112);   // 524288 B
  unsigned short* fsorted   = (unsigned short*)(ws + 822400);   // 4194304 B
  unsigned short* Wt        = (unsigned short*)(ws + 5016704);  // 245760 B

  hipMemsetAsync(ws, 0, 111616, stream);

  k0a_hist    <<<128, 256, 0, stream>>>(xyz, cellcnt);
  k0b_scan_kW <<< 68, 256, 0, stream>>>(cellcnt, cellstart, W, Wt);
  k0c_scatter <<<128, 256, 0, stream>>>(xyz, cellstart, cellfill, qorder, xyzs);
  kf_sortfeats<<<1024, 256, 0, stream>>>(feats, qorder, fsorted);
  k2_conv     <<<2048, 256, 0, stream>>>(xyzs, fsorted, kpts, cellstart,
                                         qorder, Wt, out, psum, psumsq);
  k4_norm     <<<(out_size / 4) / 256, 256, 0, stream>>>(out, psum, psumsq,
                                                         gamma, beta);
}

// Round 8
// 209.754 us; speedup vs baseline: 2.1230x; 2.1230x over previous
//
#include <hip/hip_runtime.h>

// KPConv simple block: grid ball query + KPConv(MFMA) + BN + LeakyReLU
// B=8, N=4096 -> M=32768; C_IN=64, C_OUT=128, K=15 kernel pts, nn<=34.
//
// Exact simplification: influence w = max(1 - d/0.04, 0) with ||kp||<=0.042
// => neighbors with ||rel|| >= 0.082 contribute 0; unordered within-0.082
// set (cap 34) == reference top-k result.
//
// R8 = R7 with the k4_norm grid fixed (128 -> 4096 blocks; R7 only
// normalized 1/32 of the output -> absmax 3.22).  Structure: k1_grid =
// one wave per query over its 27-cell window (9 contiguous x-ranges,
// ballot-compacted, no atomics/barriers); k2 = precomputed-list KPConv
// (R3-style) + sorted bf16 feats + 4-wide independent gathers.

#define NB     8
#define NPTS   4096
#define M_TOT  32768
#define CIN    64
#define COUT   128
#define NKP    15
#define MAXNN  34
#define NNPAD  36              // MAXNN rounded up to x4 (accum loop padding)
#define NCELL  1728            // 12^3
#define R2EFF  (0.082f * 0.082f)
#define KP_INV 25.0f           // 1 / KP_EXTENT(0.04)
#define NEG_SLOPE 0.2f
#define KTOT   960             // NKP * CIN
#define WFPAD  968             // LDS wf row stride (bf16), 16B-aligned

typedef float f32x4_t __attribute__((ext_vector_type(4)));
typedef short bf16x8_t __attribute__((ext_vector_type(8)));

__device__ __forceinline__ unsigned short f2bf(float f) {
  union { float f; unsigned u; } v; v.f = f;
  unsigned r = v.u + 0x7FFF + ((v.u >> 16) & 1);   // RNE
  return (unsigned short)(r >> 16);
}
__device__ __forceinline__ float bf2f(unsigned short s) {
  union { unsigned u; float f; } v; v.u = ((unsigned)s) << 16; return v.f;
}
__device__ __forceinline__ int cell_of(float x, float y, float z) {
  int cx = (int)(x * 12.f); cx = cx > 11 ? 11 : cx;
  int cy = (int)(y * 12.f); cy = cy > 11 ? 11 : cy;
  int cz = (int)(z * 12.f); cz = cz > 11 ? 11 : cz;
  return (cz * 12 + cy) * 12 + cx;
}

// ---------------------------------------------------------------------------
// K0a: per-cell histogram
// ---------------------------------------------------------------------------
__global__ __launch_bounds__(256) void k0a_hist(
    const float* __restrict__ xyz, int* __restrict__ cellcnt)
{
  const int pt = blockIdx.x * 256 + threadIdx.x;
  const float x = xyz[pt * 3], y = xyz[pt * 3 + 1], z = xyz[pt * 3 + 2];
  const int b = pt >> 12;
  atomicAdd(&cellcnt[b * NCELL + cell_of(x, y, z)], 1);
}

// ---------------------------------------------------------------------------
// K0b: blocks 0..7 = per-batch exclusive scan; blocks 8..67 = W transpose
// ---------------------------------------------------------------------------
__global__ __launch_bounds__(256) void k0b_scan_kW(
    const int* __restrict__ cellcnt, int* __restrict__ cellstart,
    const float* __restrict__ W, unsigned short* __restrict__ Wt)
{
  if (blockIdx.x >= 8) {
    const int idx = (blockIdx.x - 8) * 256 + threadIdx.x;  // 15360
    const int n = idx & 127, kg = idx >> 7;
    union { unsigned short s[8]; uint4 v; } u;
    #pragma unroll
    for (int j = 0; j < 8; j++)
      u.s[j] = f2bf(W[(size_t)(kg * 8 + j) * COUT + n]);
    *(uint4*)&Wt[(size_t)n * KTOT + kg * 8] = u.v;
    return;
  }
  __shared__ int ps[256];
  const int b = blockIdx.x, t = threadIdx.x;
  int local[7], s = 0;
  #pragma unroll
  for (int i = 0; i < 7; i++) {
    const int cid = t * 7 + i;
    const int c = (cid < NCELL) ? cellcnt[b * NCELL + cid] : 0;
    local[i] = c; s += c;
  }
  ps[t] = s; __syncthreads();
  for (int off = 1; off < 256; off <<= 1) {
    int v = (t >= off) ? ps[t - off] : 0;
    __syncthreads();
    ps[t] += v;
    __syncthreads();
  }
  int run = ps[t] - s;
  #pragma unroll
  for (int i = 0; i < 7; i++) {
    const int cid = t * 7 + i;
    if (cid < NCELL) { cellstart[b * 1729 + cid] = run; run += local[i]; }
  }
  if (t == 255) cellstart[b * 1729 + NCELL] = ps[255];
}

// ---------------------------------------------------------------------------
// K0c: counting-sort scatter -> qorder + sorted xyz + sorted bf16 feats
// ---------------------------------------------------------------------------
__global__ __launch_bounds__(256) void k0c_scatter(
    const float* __restrict__ xyz, const float* __restrict__ feats,
    const int* __restrict__ cellstart, int* __restrict__ cellfill,
    int* __restrict__ qorder, float4* __restrict__ xyzs,
    unsigned short* __restrict__ fsorted)
{
  const int pt = blockIdx.x * 256 + threadIdx.x;
  const float x = xyz[pt * 3], y = xyz[pt * 3 + 1], z = xyz[pt * 3 + 2];
  const int b = pt >> 12;
  const int cid = cell_of(x, y, z);
  const int slot = atomicAdd(&cellfill[b * NCELL + cid], 1);
  const int pos = b * NPTS + cellstart[b * 1729 + cid] + slot;
  qorder[pos] = pt;
  xyzs[pos] = make_float4(x, y, z, 0.f);
  const float* src = &feats[(size_t)pt * CIN];
  uint4* dst = (uint4*)&fsorted[(size_t)pos * CIN];
  #pragma unroll
  for (int g = 0; g < 8; g++) {
    float4 a = *(const float4*)(src + g * 8);
    float4 c = *(const float4*)(src + g * 8 + 4);
    union { unsigned short s[8]; uint4 v; } u;
    u.s[0] = f2bf(a.x); u.s[1] = f2bf(a.y); u.s[2] = f2bf(a.z); u.s[3] = f2bf(a.w);
    u.s[4] = f2bf(c.x); u.s[5] = f2bf(c.y); u.s[6] = f2bf(c.z); u.s[7] = f2bf(c.w);
    dst[g] = u.v;
  }
}

// ---------------------------------------------------------------------------
// K1: grid ball query, one WAVE per query.  The query's 3x3x3 cell window =
// 9 contiguous sorted x-ranges; lanes 0-8 fetch ranges, shfl-broadcast, then
// all 64 lanes test candidates in parallel; hits compacted via ballot/popc.
// No atomics, no barriers, no LDS.
// ---------------------------------------------------------------------------
__global__ __launch_bounds__(256) void k1_grid(
    const float4* __restrict__ xyzs, const int* __restrict__ cellstart,
    unsigned short* __restrict__ nlist, int* __restrict__ ncnt)
{
  const int m = blockIdx.x * 4 + (threadIdx.x >> 6);   // sorted query pos
  const int L = threadIdx.x & 63;
  const int b = m >> 12;
  const float4 Q = xyzs[m];
  int cx = (int)(Q.x * 12.f); cx = cx > 11 ? 11 : cx;
  int cy = (int)(Q.y * 12.f); cy = cy > 11 ? 11 : cy;
  int cz = (int)(Q.z * 12.f); cz = cz > 11 ? 11 : cz;

  int r0v = 0, lenv = 0;
  if (L < 9) {
    const int ny = cy + (L % 3) - 1;
    const int nz = cz + (L / 3) - 1;
    if (ny >= 0 && ny < 12 && nz >= 0 && nz < 12) {
      const int xlo = cx > 0 ? cx - 1 : 0;
      const int xhi = cx < 11 ? cx + 1 : 11;
      const int base = b * 1729 + (nz * 12 + ny) * 12;
      r0v  = cellstart[base + xlo];
      lenv = cellstart[base + xhi + 1] - r0v;
    }
  }
  int r0a[9], pfxa[10];
  pfxa[0] = 0;
  #pragma unroll
  for (int i = 0; i < 9; i++) {
    r0a[i] = __shfl(r0v, i);
    pfxa[i + 1] = pfxa[i] + __shfl(lenv, i);
  }
  const int T = pfxa[9];

  int cnt = 0;
  for (int tb = 0; tb < T; tb += 64) {
    const int t = tb + L;
    bool hit = false; int pos = 0;
    if (t < T) {
      int r = 0;
      #pragma unroll
      for (int i = 1; i < 9; i++) r += (t >= pfxa[i]);
      pos = r0a[r] + t - pfxa[r];
      const float4 P = xyzs[b * NPTS + pos];
      const float dx = P.x - Q.x, dy = P.y - Q.y, dz = P.z - Q.z;
      hit = (dx * dx + dy * dy + dz * dz) <= R2EFF;
    }
    const unsigned long long mask = __ballot(hit);
    if (hit) {
      const int slot = cnt + __popcll(mask & ((1ull << L) - 1ull));
      if (slot < MAXNN)
        nlist[(size_t)m * MAXNN + slot] = (unsigned short)(b * NPTS + pos);
    }
    cnt += __popcll(mask);
  }
  if (L == 0) ncnt[m] = cnt > MAXNN ? MAXNN : cnt;
}

// ---------------------------------------------------------------------------
// K2: KPConv from precomputed lists.  2048 blocks x 256 thr (4 waves),
// 16 sorted queries/block, ~71KB LDS -> 2 blocks/CU.
//  p1) dense parallel: (q,nn) pairs over 16x36 slots -> gidx + weight rows
//      (zero rows + self-idx for pad slots => branch-free p2)
//  p2) per wave 4 queries, lane=channel: 4 independent bf16 gathers/iter
//  p3) MFMA GEMM vs global Wt + BN partial atomics + scatter store
// ---------------------------------------------------------------------------
__global__ __launch_bounds__(256, 2) void k2_conv(
    const float4* __restrict__ xyzs, const unsigned short* __restrict__ fsorted,
    const float* __restrict__ kpts, const unsigned short* __restrict__ nlist,
    const int* __restrict__ ncnt, const int* __restrict__ qorder,
    const unsigned short* __restrict__ Wt, float* __restrict__ out,
    float* __restrict__ psum, float* __restrict__ psumsq)
{
  __shared__ float  w2[16][NNPAD][16];   // 36864 B  weight rows (f32)
  __shared__ short  wf[16][WFPAD];       // 30976 B
  __shared__ int    gidx[16][NNPAD];     //  2304 B
  __shared__ float4 qd[16];              //   256 B
  __shared__ int    qm[16];
  __shared__ int    cnts[16], cnt4[16];
  __shared__ float  kp[NKP][4];          //   240 B

  const int tid = threadIdx.x;
  const int w   = tid >> 6;
  const int L   = tid & 63;
  const int m0  = blockIdx.x * 16;

  if (tid < NKP * 3) {
    int k = tid / 3, c = tid - k * 3;
    kp[k][c] = kpts[tid];
  }
  if (tid < 16) {
    qd[tid] = xyzs[m0 + tid];
    qm[tid] = qorder[m0 + tid];
    const int c = ncnt[m0 + tid];
    cnts[tid] = c;
    cnt4[tid] = (c + 3) & ~3;
  }
  __syncthreads();

  // ---- p1: dense (q,nn) over 16 x 36 = 576 slots ----
  #pragma unroll
  for (int rep = 0; rep < 3; rep++) {
    const int p = rep * 256 + tid;
    if (p < 16 * NNPAD) {
      const int q  = p / NNPAD;
      const int nn = p - q * NNPAD;
      float wv[16];
      int g;
      if (nn < cnts[q]) {
        g = (int)nlist[(size_t)(m0 + q) * MAXNN + nn];
        const float4 P = xyzs[g];
        const float4 Qx = qd[q];
        const float rx = P.x - Qx.x, ry = P.y - Qx.y, rz = P.z - Qx.z;
        #pragma unroll
        for (int k = 0; k < NKP; k++) {
          const float dx = rx - kp[k][0];
          const float dy = ry - kp[k][1];
          const float dz = rz - kp[k][2];
          wv[k] = fmaxf(1.f - sqrtf(dx*dx + dy*dy + dz*dz) * KP_INV, 0.f);
        }
        wv[15] = 0.f;
      } else {
        g = m0 + q;                       // valid row; weights all zero
        #pragma unroll
        for (int k = 0; k < 16; k++) wv[k] = 0.f;
      }
      gidx[q][nn] = g;
      float* dst = w2[q][nn];
      *(float4*)(dst + 0)  = *(float4*)(wv + 0);
      *(float4*)(dst + 4)  = *(float4*)(wv + 4);
      *(float4*)(dst + 8)  = *(float4*)(wv + 8);
      *(float4*)(dst + 12) = *(float4*)(wv + 12);
    }
  }
  __syncthreads();

  // ---- p2: accumulation, 4 independent gathers per iteration ----
  for (int qi = 0; qi < 4; qi++) {
    const int q = w * 4 + qi;
    const int c4 = cnt4[q];
    float acc[NKP];
    #pragma unroll
    for (int k = 0; k < NKP; k++) acc[k] = 0.f;

    for (int nn = 0; nn < c4; nn += 4) {
      const int4 gg = *(const int4*)&gidx[q][nn];
      const float f0 = bf2f(fsorted[(size_t)gg.x * CIN + L]);
      const float f1 = bf2f(fsorted[(size_t)gg.y * CIN + L]);
      const float f2 = bf2f(fsorted[(size_t)gg.z * CIN + L]);
      const float f3 = bf2f(fsorted[(size_t)gg.w * CIN + L]);
      const float* r0 = w2[q][nn + 0];
      const float* r1 = w2[q][nn + 1];
      const float* r2 = w2[q][nn + 2];
      const float* r3 = w2[q][nn + 3];
      #pragma unroll
      for (int k = 0; k < NKP; k++)
        acc[k] += r0[k] * f0 + r1[k] * f1 + r2[k] * f2 + r3[k] * f3;
    }
    #pragma unroll
    for (int k = 0; k < NKP; k++)
      wf[q][k * 64 + L] = (short)f2bf(acc[k]);
  }
  __syncthreads();

  // ---- p3: MFMA GEMM out[16][128] = wf[16][960] @ W[960][128] ----
  const int ln = L & 15;
  const int kh = L >> 4;
  const int colbase = w * 32;

  f32x4_t acc2[2];
  acc2[0] = (f32x4_t){0.f, 0.f, 0.f, 0.f};
  acc2[1] = (f32x4_t){0.f, 0.f, 0.f, 0.f};

  const unsigned short* Bp0 = &Wt[(size_t)(colbase + ln) * KTOT + kh * 8];
  const unsigned short* Bp1 = Bp0 + 16 * KTOT;
  const short* Ap = &wf[ln][kh * 8];

  #pragma unroll 3
  for (int kk = 0; kk < 30; kk++) {
    const int ko = kk * 32;
    bf16x8_t b0 = *(const bf16x8_t*)(Bp0 + ko);
    bf16x8_t b1 = *(const bf16x8_t*)(Bp1 + ko);
    bf16x8_t a0 = *(const bf16x8_t*)(Ap + ko);
    acc2[0] = __builtin_amdgcn_mfma_f32_16x16x32_bf16(a0, b0, acc2[0], 0, 0, 0);
    acc2[1] = __builtin_amdgcn_mfma_f32_16x16x32_bf16(a0, b1, acc2[1], 0, 0, 0);
  }

  // BN partials: reduce 16 rows across kh via shfl, atomic into psum[128]
  float s0 = 0.f, q0 = 0.f, s1 = 0.f, q1 = 0.f;
  #pragma unroll
  for (int j = 0; j < 4; j++) {
    s0 += acc2[0][j]; q0 += acc2[0][j] * acc2[0][j];
    s1 += acc2[1][j]; q1 += acc2[1][j] * acc2[1][j];
  }
  s0 += __shfl_xor(s0, 16); s0 += __shfl_xor(s0, 32);
  q0 += __shfl_xor(q0, 16); q0 += __shfl_xor(q0, 32);
  s1 += __shfl_xor(s1, 16); s1 += __shfl_xor(s1, 32);
  q1 += __shfl_xor(q1, 16); q1 += __shfl_xor(q1, 32);
  if (kh == 0) {
    atomicAdd(&psum[colbase + ln], s0);
    atomicAdd(&psumsq[colbase + ln], q0);
    atomicAdd(&psum[colbase + 16 + ln], s1);
    atomicAdd(&psumsq[colbase + 16 + ln], q1);
  }

  // C/D layout: col = lane&15, row = (lane>>4)*4 + reg; scatter via qm[]
  #pragma unroll
  for (int c = 0; c < 2; c++) {
    #pragma unroll
    for (int j = 0; j < 4; j++) {
      const int row = kh * 4 + j;
      out[(size_t)qm[row] * COUT + colbase + c * 16 + ln] = acc2[c][j];
    }
  }
}

// ---------------------------------------------------------------------------
// K4: BN finalize (per-block, from psum) + normalize + LeakyReLU
// ---------------------------------------------------------------------------
__global__ __launch_bounds__(256) void k4_norm(
    float* __restrict__ out, const float* __restrict__ psum,
    const float* __restrict__ psumsq, const float* __restrict__ gamma,
    const float* __restrict__ beta)
{
  __shared__ float a_s[128], b_s[128];
  if (threadIdx.x < 128) {
    const int d = threadIdx.x;
    double mu  = (double)psum[d] / (double)M_TOT;
    double var = (double)psumsq[d] / (double)M_TOT - mu * mu;  // biased
    float rstd = (float)(1.0 / sqrt(var + 1e-5));
    float a = rstd * gamma[d];
    a_s[d] = a;
    b_s[d] = beta[d] - (float)mu * a;
  }
  __syncthreads();
  const int idx = blockIdx.x * 256 + threadIdx.x;   // float4 index
  float4 v = ((const float4*)out)[idx];
  const int d0 = (idx * 4) & 127;
  float y0 = v.x * a_s[d0 + 0] + b_s[d0 + 0];
  float y1 = v.y * a_s[d0 + 1] + b_s[d0 + 1];
  float y2 = v.z * a_s[d0 + 2] + b_s[d0 + 2];
  float y3 = v.w * a_s[d0 + 3] + b_s[d0 + 3];
  v.x = y0 >= 0.f ? y0 : NEG_SLOPE * y0;
  v.y = y1 >= 0.f ? y1 : NEG_SLOPE * y1;
  v.z = y2 >= 0.f ? y2 : NEG_SLOPE * y2;
  v.w = y3 >= 0.f ? y3 : NEG_SLOPE * y3;
  ((float4*)out)[idx] = v;
}

// ---------------------------------------------------------------------------
extern "C" void kernel_launch(void* const* d_in, const int* in_sizes, int n_in,
                              void* d_out, int out_size, void* d_ws,
                              size_t ws_size, hipStream_t stream)
{
  const float* xyz   = (const float*)d_in[0];
  const float* feats = (const float*)d_in[1];
  const float* kpts  = (const float*)d_in[2];
  const float* W     = (const float*)d_in[3];
  const float* gamma = (const float*)d_in[4];
  const float* beta  = (const float*)d_in[5];
  float* out = (float*)d_out;

  char* ws = (char*)d_ws;
  int*            cellcnt   = (int*)(ws + 0);           //  55296 B ─┐
  int*            cellfill  = (int*)(ws + 55296);       //  55296 B  │ zeroed
  float*          psum      = (float*)(ws + 110592);    //    512 B  │
  float*          psumsq    = (float*)(ws + 111104);    //    512 B ─┘
  int*            cellstart = (int*)(ws + 111616);      //  55424 B
  int*            qorder    = (int*)(ws + 167040);      // 131072 B
  float4*         xyzs      = (float4*)(ws + 298112);   // 524288 B
  unsigned short* fsorted   = (unsigned short*)(ws + 822400);   // 4194304 B
  unsigned short* Wt        = (unsigned short*)(ws + 5016704);  // 245760 B
  unsigned short* nlist     = (unsigned short*)(ws + 5262464);  // 2228224 B
  int*            ncnt      = (int*)(ws + 7490688);     // 131072 B

  hipMemsetAsync(ws, 0, 111616, stream);

  k0a_hist   <<< 128, 256, 0, stream>>>(xyz, cellcnt);
  k0b_scan_kW<<<  68, 256, 0, stream>>>(cellcnt, cellstart, W, Wt);
  k0c_scatter<<< 128, 256, 0, stream>>>(xyz, feats, cellstart, cellfill,
                                        qorder, xyzs, fsorted);
  k1_grid    <<<8192, 256, 0, stream>>>(xyzs, cellstart, nlist, ncnt);
  k2_conv    <<<2048, 256, 0, stream>>>(xyzs, fsorted, kpts, nlist, ncnt,
                                        qorder, Wt, out, psum, psumsq);
  k4_norm    <<<(out_size / 4) / 256, 256, 0, stream>>>(out, psum, psumsq,
                                                        gamma, beta);
}